// Round 3
// baseline (8515.167 us; speedup 1.0000x reference)
//
#include <hip/hip_runtime.h>

// ---------------- problem constants ----------------
#define TT   512
#define BB   64
#define HH1  512
#define HH2  256
#define DD   204
#define DXP  224          // x K padded to x32
#define KO_X (DXP/8)      // 28 k-octets for x
#define G1B  32           // layer1 blocks (16 units each)
#define G2B  32           // layer2 blocks (8 units each)
#define ST1R 520          // LDS stride (halfs) for Whh1 rows (512+8)
#define ST2R 776          // LDS stride for [Wih2|Whh2] rows (768+8)
#define STXR 232          // LDS stride for Wih1 rows in xg GEMM (224+8)
#define FCN  512

typedef _Float16 half8 __attribute__((ext_vector_type(8)));
typedef float    f32x4 __attribute__((ext_vector_type(4)));

// activations in MFMA-A layout: [k-octet][row][8]
__device__ __align__(16) _Float16 g_xAhi[KO_X][TT*BB][8];
__device__ __align__(16) _Float16 g_xAlo[KO_X][TT*BB][8];
// xg = x@Wih1 (permuted): [t][blk][col(unit-perm)][batch]  -> lane reads float4 over batch
__device__ __align__(16) float g_xg[TT][G1B][64][64];
__device__ __align__(16) _Float16 g_h1hi[TT+1][HH1/8][BB][8];
__device__ __align__(16) _Float16 g_h1lo[TT+1][HH1/8][BB][8];
__device__ __align__(16) _Float16 g_h2hi[TT+1][HH2/8][BB][8];
__device__ __align__(16) _Float16 g_h2lo[TT+1][HH2/8][BB][8];
__device__ float    g_z[BB][FCN];
__device__ unsigned g_ctr1[TT+1];   // [t]: L1 blocks done with step t; [TT]: prologue (64)
__device__ unsigned g_ctr2[TT+1];

__device__ __forceinline__ float sigm(float x){ return 1.0f/(1.0f + __expf(-x)); }
__device__ __forceinline__ float tanha(float x){ return 1.0f - 2.0f/(__expf(2.0f*x) + 1.0f); }

// write-through publish (performed at coherence point); no fence
__device__ __forceinline__ void awrite(unsigned* p, unsigned v){
  __hip_atomic_store(p, v, __ATOMIC_RELAXED, __HIP_MEMORY_SCOPE_AGENT);
}
// relaxed spin; NO acquire (consumers read only write-once addresses)
__device__ __forceinline__ void wait_ctr(unsigned* c, unsigned target){
  while (__hip_atomic_load(c, __ATOMIC_RELAXED, __HIP_MEMORY_SCOPE_AGENT) < target)
    __builtin_amdgcn_s_sleep(1);
  asm volatile("" ::: "memory");
}
__device__ __forceinline__ unsigned short h16(_Float16 h){
  union { _Float16 f; unsigned short u; } cv; cv.f = h; return cv.u;
}

#define MFMA16 __builtin_amdgcn_mfma_f32_16x16x32_f16

// ---------- split x into hi/lo f16 planes, MFMA-A layout (row = t*BB+b) ----------
__global__ __launch_bounds__(256) void k_split(const float* __restrict__ x){
  int t = blockIdx.x;
  for (int idx = threadIdx.x; idx < BB*DXP; idx += 256){
    int b = idx / DXP, d = idx - b*DXP;
    float v = (d < DD) ? x[(b*TT + t)*DD + d] : 0.f;
    _Float16 hi = (_Float16)v;
    _Float16 lo = (_Float16)(v - (float)hi);
    g_xAhi[d>>3][t*BB + b][d&7] = hi;
    g_xAlo[d>>3][t*BB + b][d&7] = lo;
  }
}

// ---------- xg = x @ Wih1^T, output permuted to scan layout ----------
__global__ __launch_bounds__(256) void k_xg(const float* __restrict__ Wih1){
  __shared__ _Float16 sBh[64*STXR];
  __shared__ _Float16 sBl[64*STXR];
  const int tid = threadIdx.x;
  const int blk = blockIdx.x & 31, tc = blockIdx.x >> 5;
  for (int idx = tid; idx < 64*DXP; idx += 256){
    int r = idx / DXP, k = idx - r*DXP;
    int tile = r >> 4, nn = r & 15;
    int gate = (tile&1) + ((nn>>3)<<1);
    int unit = ((tile>>1)<<3) + (nn&7);
    int grow = gate*HH1 + blk*16 + unit;
    float v = (k < DD) ? Wih1[grow*DD + k] : 0.f;
    _Float16 hi = (_Float16)v;
    sBh[r*STXR + k] = hi;
    sBl[r*STXR + k] = (_Float16)(v - (float)hi);
  }
  __syncthreads();
  const int l = tid & 63, w = tid >> 6, n = l & 15, kq = l >> 4;
  for (int t = tc*64; t < tc*64 + 64; ++t){
    f32x4 a0[4], a1[4], a2[4];
    #pragma unroll
    for (int mt = 0; mt < 4; ++mt){ a0[mt]=(f32x4){0,0,0,0}; a1[mt]=a0[mt]; a2[mt]=a0[mt]; }
    #pragma unroll
    for (int ks = 0; ks < 7; ++ks){
      int o = ks*4 + kq, kb = ks*32 + kq*8;
      half8 bh = *(const half8*)&sBh[(w*16+n)*STXR + kb];
      half8 bl = *(const half8*)&sBl[(w*16+n)*STXR + kb];
      #pragma unroll
      for (int mt = 0; mt < 4; ++mt){
        half8 ah = *(const half8*)&g_xAhi[o][t*BB + mt*16 + n][0];
        half8 al = *(const half8*)&g_xAlo[o][t*BB + mt*16 + n][0];
        a0[mt] = MFMA16(ah, bh, a0[mt], 0,0,0);
        a1[mt] = MFMA16(ah, bl, a1[mt], 0,0,0);
        a2[mt] = MFMA16(al, bh, a2[mt], 0,0,0);
      }
    }
    #pragma unroll
    for (int mt = 0; mt < 4; ++mt){
      float4 v4;
      v4.x = (a0[mt][0] + a1[mt][0]) + a2[mt][0];
      v4.y = (a0[mt][1] + a1[mt][1]) + a2[mt][1];
      v4.z = (a0[mt][2] + a1[mt][2]) + a2[mt][2];
      v4.w = (a0[mt][3] + a1[mt][3]) + a2[mt][3];
      *(float4*)&g_xg[t][blk][w*16 + n][mt*16 + kq*4] = v4;
    }
  }
}

// ---------- sequential scan: roles by bid%8 so each layer is (typically) one XCD ----------
__global__ __launch_bounds__(256) void k_scan(
    const float* __restrict__ Whh1, const float* __restrict__ bih1, const float* __restrict__ bhh1,
    const float* __restrict__ Wih2, const float* __restrict__ Whh2,
    const float* __restrict__ bih2, const float* __restrict__ bhh2)
{
  __shared__ _Float16 sWhi[64*ST1R];
  __shared__ _Float16 sWlo[64*ST1R];

  const int grp  = blockIdx.x & 7;
  const int slot = blockIdx.x >> 3;      // 0..31
  if (grp >= 2) return;

  const int tid = threadIdx.x;
  const int l   = tid & 63;
  const int w   = tid >> 6;      // wave = M-tile (batches w*16..)
  const int n   = l & 15;
  const int kq  = l >> 4;
  const int mrow = w*16 + n;
  const int mout = w*16 + kq*4;  // + r

  // ---- zero initial states (write-through so all XCDs see them) ----
  {
    int eidx = (grp*G1B + slot)*256 + tid;     // 0..16383 over elected blocks
    unsigned* z1h = (unsigned*)&g_h1hi[0][0][0][0];
    unsigned* z1l = (unsigned*)&g_h1lo[0][0][0][0];
    if (eidx < (HH1*BB)/2){ awrite(z1h+eidx, 0u); awrite(z1l+eidx, 0u); }
    unsigned* z2h = (unsigned*)&g_h2hi[0][0][0][0];
    unsigned* z2l = (unsigned*)&g_h2lo[0][0][0][0];
    if (eidx < (HH2*BB)/2){ awrite(z2h+eidx, 0u); awrite(z2l+eidx, 0u); }
  }

  if (grp == 0){
    // ============ LAYER 1: units [slot*16, slot*16+16), 4 N-tiles ============
    const int ub = slot*16;
    for (int idx = tid; idx < 64*HH1; idx += 256){
      int r = idx >> 9, k = idx & 511;
      int tile = r >> 4, nn = r & 15;
      int gate = (tile&1) + ((nn>>3)<<1);
      int unit = ((tile>>1)<<3) + (nn&7);
      int grow = gate*HH1 + ub + unit;
      float v = Whh1[grow*HH1 + k];
      _Float16 hi = (_Float16)v;
      sWhi[r*ST1R + k] = hi;
      sWlo[r*ST1R + k] = (_Float16)(v - (float)hi);
    }
    float bias[4];
    #pragma unroll
    for (int tl = 0; tl < 4; ++tl){
      int gate = (tl&1) + ((n>>3)<<1);
      int unit = ((tl>>1)<<3) + (n&7);
      int gi = gate*HH1 + ub + unit;
      bias[tl] = bih1[gi] + bhh1[gi];
    }
    // prefetch xg[0] into regs
    float4 xgv[4];
    #pragma unroll
    for (int tl = 0; tl < 4; ++tl)
      xgv[tl] = *(const float4*)&g_xg[0][slot][tl*16 + n][mout];

    asm volatile("s_waitcnt vmcnt(0)" ::: "memory");
    __syncthreads();
    if (tid == 0){
      __hip_atomic_fetch_add(&g_ctr1[TT], 1u, __ATOMIC_RELAXED, __HIP_MEMORY_SCOPE_AGENT);
      wait_ctr(&g_ctr1[TT], G1B + G2B);
    }
    __syncthreads();

    float cst[2][4] = {{0,0,0,0},{0,0,0,0}};
    for (int t = 0; t < TT; ++t){
      if (t > 0){
        if (tid == 0) wait_ctr(&g_ctr1[t-1], G1B);
        __syncthreads();
      }
      // prefetch xg[t+1]
      float4 xgn[4];
      if (t+1 < TT){
        #pragma unroll
        for (int tl = 0; tl < 4; ++tl)
          xgn[tl] = *(const float4*)&g_xg[t+1][slot][tl*16 + n][mout];
      }

      f32x4 a0[4], a1[4], a2[4];
      #pragma unroll
      for (int tl = 0; tl < 4; ++tl){ a0[tl]=(f32x4){0,0,0,0}; a1[tl]=a0[tl]; a2[tl]=a0[tl]; }
      const half8* Ah = (const half8*)&g_h1hi[t][0][0][0];
      const half8* Al = (const half8*)&g_h1lo[t][0][0][0];
      #pragma unroll 4
      for (int ks = 0; ks < 16; ++ks){
        half8 ah = Ah[(ks*4+kq)*BB + mrow];
        half8 al = Al[(ks*4+kq)*BB + mrow];
        int kb = ks*32 + kq*8;
        #pragma unroll
        for (int tl = 0; tl < 4; ++tl){
          half8 bh = *(const half8*)&sWhi[(tl*16+n)*ST1R + kb];
          half8 bl = *(const half8*)&sWlo[(tl*16+n)*ST1R + kb];
          a0[tl] = MFMA16(ah, bh, a0[tl], 0,0,0);
          a1[tl] = MFMA16(ah, bl, a1[tl], 0,0,0);
          a2[tl] = MFMA16(al, bh, a2[tl], 0,0,0);
        }
      }
      #pragma unroll
      for (int j = 0; j < 2; ++j){
        #pragma unroll
        for (int r = 0; r < 4; ++r){
          float v0 = ((a0[2*j][r]+a1[2*j][r])+a2[2*j][r]) + bias[2*j]   + ((const float*)&xgv[2*j])[r];
          float v1 = ((a0[2*j+1][r]+a1[2*j+1][r])+a2[2*j+1][r]) + bias[2*j+1] + ((const float*)&xgv[2*j+1])[r];
          float av = (n < 8) ? sigm(v0) : tanha(v0);
          float bv = sigm(v1);
          float pa = __shfl_xor(av, 8);
          float cn = bv*cst[j][r] + av*pa;
          float tc = tanha(cn);
          if (n < 8) cst[j][r] = cn;
          float tcx = __shfl_xor(tc, 8);
          float hv = bv * tcx;                 // valid on n>=8
          float hx = __shfl_xor(hv, 1);
          if (n >= 8 && !(n & 1)){
            _Float16 h0 = (_Float16)hv; _Float16 l0 = (_Float16)(hv - (float)h0);
            _Float16 h1v = (_Float16)hx; _Float16 l1 = (_Float16)(hx - (float)h1v);
            unsigned hw = (unsigned)h16(h0) | ((unsigned)h16(h1v) << 16);
            unsigned lw = (unsigned)h16(l0) | ((unsigned)h16(l1) << 16);
            int m = mout + r;
            awrite((unsigned*)&g_h1hi[t+1][slot*2+j][m][0] + ((n&7)>>1), hw);
            awrite((unsigned*)&g_h1lo[t+1][slot*2+j][m][0] + ((n&7)>>1), lw);
          }
        }
      }
      #pragma unroll
      for (int tl = 0; tl < 4; ++tl) xgv[tl] = xgn[tl];
      asm volatile("s_waitcnt vmcnt(0)" ::: "memory");
      __syncthreads();
      if (tid == 0)
        __hip_atomic_fetch_add(&g_ctr1[t], 1u, __ATOMIC_RELAXED, __HIP_MEMORY_SCOPE_AGENT);
    }
  } else {
    // ============ LAYER 2: units [slot*8, slot*8+8), 2 N-tiles ============
    const int b2 = slot;
    const int ub = b2*8;
    for (int idx = tid; idx < 32*768; idx += 256){
      int r = idx / 768, k = idx - r*768;
      int tile = r >> 4, nn = r & 15;
      int gate = (tile&1) + ((nn>>3)<<1);
      int grow = gate*HH2 + ub + (nn&7);
      float v = (k < HH1) ? Wih2[grow*HH1 + k] : Whh2[grow*HH2 + (k-HH1)];
      _Float16 hi = (_Float16)v;
      sWhi[r*ST2R + k] = hi;
      sWlo[r*ST2R + k] = (_Float16)(v - (float)hi);
    }
    float bias[2];
    #pragma unroll
    for (int tl = 0; tl < 2; ++tl){
      int gate = (tl&1) + ((n>>3)<<1);
      int gi = gate*HH2 + ub + (n&7);
      bias[tl] = bih2[gi] + bhh2[gi];
    }
    asm volatile("s_waitcnt vmcnt(0)" ::: "memory");
    __syncthreads();
    if (tid == 0){
      __hip_atomic_fetch_add(&g_ctr1[TT], 1u, __ATOMIC_RELAXED, __HIP_MEMORY_SCOPE_AGENT);
      wait_ctr(&g_ctr1[TT], G1B + G2B);
    }
    __syncthreads();

    float cst[4] = {0,0,0,0};
    for (int t = 0; t < TT; ++t){
      if (tid == 0){
        wait_ctr(&g_ctr1[t], G1B);               // h1_t (= slot t+1) published
        if (t > 0) wait_ctr(&g_ctr2[t-1], G2B);  // h2_t published
      }
      __syncthreads();

      f32x4 a0[2], a1[2], a2[2];
      #pragma unroll
      for (int tl = 0; tl < 2; ++tl){ a0[tl]=(f32x4){0,0,0,0}; a1[tl]=a0[tl]; a2[tl]=a0[tl]; }
      const half8* Ah = (const half8*)&g_h1hi[t+1][0][0][0];
      const half8* Al = (const half8*)&g_h1lo[t+1][0][0][0];
      #pragma unroll 4
      for (int ks = 0; ks < 16; ++ks){
        half8 ah = Ah[(ks*4+kq)*BB + mrow];
        half8 al = Al[(ks*4+kq)*BB + mrow];
        int kb = ks*32 + kq*8;
        #pragma unroll
        for (int tl = 0; tl < 2; ++tl){
          half8 bh = *(const half8*)&sWhi[(tl*16+n)*ST2R + kb];
          half8 bl = *(const half8*)&sWlo[(tl*16+n)*ST2R + kb];
          a0[tl] = MFMA16(ah, bh, a0[tl], 0,0,0);
          a1[tl] = MFMA16(ah, bl, a1[tl], 0,0,0);
          a2[tl] = MFMA16(al, bh, a2[tl], 0,0,0);
        }
      }
      const half8* Bh = (const half8*)&g_h2hi[t][0][0][0];
      const half8* Bl = (const half8*)&g_h2lo[t][0][0][0];
      #pragma unroll 4
      for (int ks = 0; ks < 8; ++ks){
        half8 ah = Bh[(ks*4+kq)*BB + mrow];
        half8 al = Bl[(ks*4+kq)*BB + mrow];
        int kb = HH1 + ks*32 + kq*8;
        #pragma unroll
        for (int tl = 0; tl < 2; ++tl){
          half8 bh = *(const half8*)&sWhi[(tl*16+n)*ST2R + kb];
          half8 bl = *(const half8*)&sWlo[(tl*16+n)*ST2R + kb];
          a0[tl] = MFMA16(ah, bh, a0[tl], 0,0,0);
          a1[tl] = MFMA16(ah, bl, a1[tl], 0,0,0);
          a2[tl] = MFMA16(al, bh, a2[tl], 0,0,0);
        }
      }
      #pragma unroll
      for (int r = 0; r < 4; ++r){
        float v0 = ((a0[0][r]+a1[0][r])+a2[0][r]) + bias[0];
        float v1 = ((a0[1][r]+a1[1][r])+a2[1][r]) + bias[1];
        float av = (n < 8) ? sigm(v0) : tanha(v0);
        float bv = sigm(v1);
        float pa = __shfl_xor(av, 8);
        float cn = bv*cst[r] + av*pa;
        float tc = tanha(cn);
        if (n < 8) cst[r] = cn;
        float tcx = __shfl_xor(tc, 8);
        float hv = bv * tcx;
        float hx = __shfl_xor(hv, 1);
        if (n >= 8 && !(n & 1)){
          _Float16 h0 = (_Float16)hv; _Float16 l0 = (_Float16)(hv - (float)h0);
          _Float16 h1v = (_Float16)hx; _Float16 l1 = (_Float16)(hx - (float)h1v);
          unsigned hw = (unsigned)h16(h0) | ((unsigned)h16(h1v) << 16);
          unsigned lw = (unsigned)h16(l0) | ((unsigned)h16(l1) << 16);
          int m = mout + r;
          awrite((unsigned*)&g_h2hi[t+1][b2][m][0] + ((n&7)>>1), hw);
          awrite((unsigned*)&g_h2lo[t+1][b2][m][0] + ((n&7)>>1), lw);
        }
      }
      asm volatile("s_waitcnt vmcnt(0)" ::: "memory");
      __syncthreads();
      if (tid == 0)
        __hip_atomic_fetch_add(&g_ctr2[t], 1u, __ATOMIC_RELAXED, __HIP_MEMORY_SCOPE_AGENT);
    }
  }
}

// z = relu(h2_T @ Wfc1^T + bfc1)
__global__ __launch_bounds__(256) void k_fc1(const float* __restrict__ Wfc1, const float* __restrict__ bfc1){
  int b = blockIdx.x;
  for (int task = threadIdx.x; task < 512; task += 256){
    int m = task >> 3, cc = b*8 + (task & 7);
    float acc = bfc1[cc];
    const float* wr = &Wfc1[cc*HH2];
    for (int k = 0; k < HH2; ++k){
      float hvv = (float)g_h2hi[TT][k>>3][m][k&7] + (float)g_h2lo[TT][k>>3][m][k&7];
      acc += hvv * wr[k];
    }
    g_z[m][cc] = fmaxf(acc, 0.f);
  }
}

__global__ __launch_bounds__(256) void k_fc2(const float* __restrict__ Wfc2, const float* __restrict__ bfc2,
                                             float* __restrict__ out){
  for (int task = threadIdx.x; task < BB*7; task += 256){
    int m = task / 7, oc = task % 7;
    float acc = bfc2[oc];
    const float* wr = &Wfc2[oc*FCN];
    const float* zr = &g_z[m][0];
    for (int k = 0; k < FCN; ++k) acc += zr[k]*wr[k];
    out[m*7 + oc] = acc;
  }
  for (int i = threadIdx.x; i < TT+1; i += 256){ g_ctr1[i] = 0u; g_ctr2[i] = 0u; }
}

extern "C" void kernel_launch(void* const* d_in, const int* in_sizes, int n_in,
                              void* d_out, int out_size, void* d_ws, size_t ws_size,
                              hipStream_t stream){
  (void)in_sizes; (void)n_in; (void)out_size; (void)d_ws; (void)ws_size;
  const float* x    = (const float*)d_in[0];
  const float* Wih1 = (const float*)d_in[1];
  const float* Whh1 = (const float*)d_in[2];
  const float* bih1 = (const float*)d_in[3];
  const float* bhh1 = (const float*)d_in[4];
  const float* Wih2 = (const float*)d_in[5];
  const float* Whh2 = (const float*)d_in[6];
  const float* bih2 = (const float*)d_in[7];
  const float* bhh2 = (const float*)d_in[8];
  const float* Wfc1 = (const float*)d_in[9];
  const float* bfc1 = (const float*)d_in[10];
  const float* Wfc2 = (const float*)d_in[11];
  const float* bfc2 = (const float*)d_in[12];

  hipLaunchKernelGGL(k_split, dim3(TT), dim3(256), 0, stream, x);
  hipLaunchKernelGGL(k_xg,    dim3(G1B*8), dim3(256), 0, stream, Wih1);
  hipLaunchKernelGGL(k_scan,  dim3(256), dim3(256), 0, stream,
                     Whh1, bih1, bhh1, Wih2, Whh2, bih2, bhh2);
  hipLaunchKernelGGL(k_fc1,   dim3(FCN/8), dim3(256), 0, stream, Wfc1, bfc1);
  hipLaunchKernelGGL(k_fc2,   dim3(1), dim3(256), 0, stream, Wfc2, bfc2, (float*)d_out);
}

// Round 4
// 7254.213 us; speedup vs baseline: 1.1738x; 1.1738x over previous
//
#include <hip/hip_runtime.h>

// ---------------- problem constants ----------------
#define TT   512
#define BB   64
#define HH1  512
#define HH2  256
#define DD   204
#define DXP  224          // x K padded to x32
#define KO_X (DXP/8)      // 28 k-octets for x
#define G1B  32           // layer1 blocks (16 units each)
#define G2B  32           // layer2 blocks (8 units each)
#define NBLK (G1B+G2B)
#define ST1R 520          // LDS stride (halfs) for Whh1 rows (512+8)
#define ST2R 776          // LDS stride for [Wih2|Whh2] rows (768+8)
#define STXR 232          // LDS stride for Wih1 rows in xg GEMM (224+8)
#define FCN  512

typedef _Float16 half8 __attribute__((ext_vector_type(8)));
typedef float    f32x4 __attribute__((ext_vector_type(4)));

// activations in MFMA-A layout: [k-octet][row][8]
__device__ __align__(16) _Float16 g_xAhi[KO_X][TT*BB][8];
__device__ __align__(16) _Float16 g_xAlo[KO_X][TT*BB][8];
// xg = x@Wih1 (permuted): [t][blk][col(unit-perm)][batch]
__device__ __align__(16) float g_xg[TT][G1B][64][64];
__device__ __align__(16) _Float16 g_h1hi[TT+1][HH1/8][BB][8];
__device__ __align__(16) _Float16 g_h1lo[TT+1][HH1/8][BB][8];
__device__ __align__(16) _Float16 g_h2hi[TT+1][HH2/8][BB][8];
__device__ __align__(16) _Float16 g_h2lo[TT+1][HH2/8][BB][8];
__device__ float    g_z[BB][FCN];

// one counter per 128B line: pollers and RMWs on step t never touch step t' lines
struct __align__(128) Ctr { unsigned v; unsigned pad[31]; };
__device__ Ctr g_ctr1[TT+1];   // [t]: L1 blocks done with step t; [TT]: prologue (64)
__device__ Ctr g_ctr2[TT+1];
__device__ Ctr g_prog;         // single-writer: highest h1 slot fully published

__device__ __forceinline__ float sigm(float x){ return 1.0f/(1.0f + __expf(-x)); }
__device__ __forceinline__ float tanha(float x){ return 1.0f - 2.0f/(__expf(2.0f*x) + 1.0f); }

// write-through publish (performed at coherence point); no fence
__device__ __forceinline__ void awrite(unsigned* p, unsigned v){
  __hip_atomic_store(p, v, __ATOMIC_RELAXED, __HIP_MEMORY_SCOPE_AGENT);
}
// relaxed spin with backoff; NO acquire (consumers read only write-once addresses)
__device__ __forceinline__ void wait_ge(unsigned* c, unsigned target){
  while (__hip_atomic_load(c, __ATOMIC_RELAXED, __HIP_MEMORY_SCOPE_AGENT) < target)
    __builtin_amdgcn_s_sleep(8);
  asm volatile("" ::: "memory");
}
__device__ __forceinline__ unsigned short h16(_Float16 h){
  union { _Float16 f; unsigned short u; } cv; cv.f = h; return cv.u;
}

#define MFMA16 __builtin_amdgcn_mfma_f32_16x16x32_f16

// ---------- split x into hi/lo f16 planes, MFMA-A layout (row = t*BB+b) ----------
__global__ __launch_bounds__(256) void k_split(const float* __restrict__ x){
  int t = blockIdx.x;
  for (int idx = threadIdx.x; idx < BB*DXP; idx += 256){
    int b = idx / DXP, d = idx - b*DXP;
    float v = (d < DD) ? x[(b*TT + t)*DD + d] : 0.f;
    _Float16 hi = (_Float16)v;
    _Float16 lo = (_Float16)(v - (float)hi);
    g_xAhi[d>>3][t*BB + b][d&7] = hi;
    g_xAlo[d>>3][t*BB + b][d&7] = lo;
  }
}

// ---------- xg = x @ Wih1^T, output permuted to scan layout ----------
__global__ __launch_bounds__(256) void k_xg(const float* __restrict__ Wih1){
  __shared__ _Float16 sBh[64*STXR];
  __shared__ _Float16 sBl[64*STXR];
  const int tid = threadIdx.x;
  const int blk = blockIdx.x & 31, tc = blockIdx.x >> 5;
  for (int idx = tid; idx < 64*DXP; idx += 256){
    int r = idx / DXP, k = idx - r*DXP;
    int tile = r >> 4, nn = r & 15;
    int gate = (tile&1) + ((nn>>3)<<1);
    int unit = ((tile>>1)<<3) + (nn&7);
    int grow = gate*HH1 + blk*16 + unit;
    float v = (k < DD) ? Wih1[grow*DD + k] : 0.f;
    _Float16 hi = (_Float16)v;
    sBh[r*STXR + k] = hi;
    sBl[r*STXR + k] = (_Float16)(v - (float)hi);
  }
  __syncthreads();
  const int l = tid & 63, w = tid >> 6, n = l & 15, kq = l >> 4;
  for (int t = tc*64; t < tc*64 + 64; ++t){
    f32x4 a0[4], a1[4], a2[4];
    #pragma unroll
    for (int mt = 0; mt < 4; ++mt){ a0[mt]=(f32x4){0,0,0,0}; a1[mt]=a0[mt]; a2[mt]=a0[mt]; }
    #pragma unroll
    for (int ks = 0; ks < 7; ++ks){
      int o = ks*4 + kq, kb = ks*32 + kq*8;
      half8 bh = *(const half8*)&sBh[(w*16+n)*STXR + kb];
      half8 bl = *(const half8*)&sBl[(w*16+n)*STXR + kb];
      #pragma unroll
      for (int mt = 0; mt < 4; ++mt){
        half8 ah = *(const half8*)&g_xAhi[o][t*BB + mt*16 + n][0];
        half8 al = *(const half8*)&g_xAlo[o][t*BB + mt*16 + n][0];
        a0[mt] = MFMA16(ah, bh, a0[mt], 0,0,0);
        a1[mt] = MFMA16(ah, bl, a1[mt], 0,0,0);
        a2[mt] = MFMA16(al, bh, a2[mt], 0,0,0);
      }
    }
    #pragma unroll
    for (int mt = 0; mt < 4; ++mt){
      float4 v4;
      v4.x = (a0[mt][0] + a1[mt][0]) + a2[mt][0];
      v4.y = (a0[mt][1] + a1[mt][1]) + a2[mt][1];
      v4.z = (a0[mt][2] + a1[mt][2]) + a2[mt][2];
      v4.w = (a0[mt][3] + a1[mt][3]) + a2[mt][3];
      *(float4*)&g_xg[t][blk][w*16 + n][mt*16 + kq*4] = v4;
    }
  }
}

// ---------- sequential scan: 64 spread blocks; bid<32 = layer1, else layer2 ----------
__global__ __launch_bounds__(256) void k_scan(
    const float* __restrict__ Whh1, const float* __restrict__ bih1, const float* __restrict__ bhh1,
    const float* __restrict__ Wih2, const float* __restrict__ Whh2,
    const float* __restrict__ bih2, const float* __restrict__ bhh2)
{
  __shared__ _Float16 sWhi[64*ST1R];
  __shared__ _Float16 sWlo[64*ST1R];

  const int bid = blockIdx.x;
  const int tid = threadIdx.x;
  const int l   = tid & 63;
  const int w   = tid >> 6;      // wave = M-tile (batches w*16..)
  const int n   = l & 15;
  const int kq  = l >> 4;
  const int mrow = w*16 + n;
  const int mout = w*16 + kq*4;  // + r

  // ---- zero initial states (write-through so all XCDs see them) ----
  {
    int eidx = bid*256 + tid;
    unsigned* z1h = (unsigned*)&g_h1hi[0][0][0][0];
    unsigned* z1l = (unsigned*)&g_h1lo[0][0][0][0];
    if (eidx < (HH1*BB)/2){ awrite(z1h+eidx, 0u); awrite(z1l+eidx, 0u); }
    unsigned* z2h = (unsigned*)&g_h2hi[0][0][0][0];
    unsigned* z2l = (unsigned*)&g_h2lo[0][0][0][0];
    if (eidx < (HH2*BB)/2){ awrite(z2h+eidx, 0u); awrite(z2l+eidx, 0u); }
  }

  if (bid < G1B){
    // ============ LAYER 1: units [slot*16, slot*16+16), 4 N-tiles ============
    const int slot = bid;
    const int ub = slot*16;
    for (int idx = tid; idx < 64*HH1; idx += 256){
      int r = idx >> 9, k = idx & 511;
      int tile = r >> 4, nn = r & 15;
      int gate = (tile&1) + ((nn>>3)<<1);
      int unit = ((tile>>1)<<3) + (nn&7);
      int grow = gate*HH1 + ub + unit;
      float v = Whh1[grow*HH1 + k];
      _Float16 hi = (_Float16)v;
      sWhi[r*ST1R + k] = hi;
      sWlo[r*ST1R + k] = (_Float16)(v - (float)hi);
    }
    float bias[4];
    #pragma unroll
    for (int tl = 0; tl < 4; ++tl){
      int gate = (tl&1) + ((n>>3)<<1);
      int unit = ((tl>>1)<<3) + (n&7);
      int gi = gate*HH1 + ub + unit;
      bias[tl] = bih1[gi] + bhh1[gi];
    }
    // prefetch xg[0] into regs
    float4 xgv[4];
    #pragma unroll
    for (int tl = 0; tl < 4; ++tl)
      xgv[tl] = *(const float4*)&g_xg[0][slot][tl*16 + n][mout];

    asm volatile("s_waitcnt vmcnt(0)" ::: "memory");
    __syncthreads();
    if (tid == 0){
      __hip_atomic_fetch_add(&g_ctr1[TT].v, 1u, __ATOMIC_RELAXED, __HIP_MEMORY_SCOPE_AGENT);
      wait_ge(&g_ctr1[TT].v, NBLK);
    }
    __syncthreads();

    float cst[2][4] = {{0,0,0,0},{0,0,0,0}};
    for (int t = 0; t < TT; ++t){
      if (t > 0){
        if (tid == 0){
          wait_ge(&g_ctr1[t-1].v, G1B);
          if (slot == 0) awrite(&g_prog.v, (unsigned)t);   // single-writer feed for L2
        }
        __syncthreads();
      }
      // prefetch xg[t+1]
      float4 xgn[4];
      if (t+1 < TT){
        #pragma unroll
        for (int tl = 0; tl < 4; ++tl)
          xgn[tl] = *(const float4*)&g_xg[t+1][slot][tl*16 + n][mout];
      }

      f32x4 a0[4], a1[4], a2[4];
      #pragma unroll
      for (int tl = 0; tl < 4; ++tl){ a0[tl]=(f32x4){0,0,0,0}; a1[tl]=a0[tl]; a2[tl]=a0[tl]; }
      const half8* Ah = (const half8*)&g_h1hi[t][0][0][0];
      const half8* Al = (const half8*)&g_h1lo[t][0][0][0];
      #pragma unroll 4
      for (int ks = 0; ks < 16; ++ks){
        half8 ah = Ah[(ks*4+kq)*BB + mrow];
        half8 al = Al[(ks*4+kq)*BB + mrow];
        int kb = ks*32 + kq*8;
        #pragma unroll
        for (int tl = 0; tl < 4; ++tl){
          half8 bh = *(const half8*)&sWhi[(tl*16+n)*ST1R + kb];
          half8 bl = *(const half8*)&sWlo[(tl*16+n)*ST1R + kb];
          a0[tl] = MFMA16(ah, bh, a0[tl], 0,0,0);
          a1[tl] = MFMA16(ah, bl, a1[tl], 0,0,0);
          a2[tl] = MFMA16(al, bh, a2[tl], 0,0,0);
        }
      }
      #pragma unroll
      for (int j = 0; j < 2; ++j){
        #pragma unroll
        for (int r = 0; r < 4; ++r){
          float v0 = ((a0[2*j][r]+a1[2*j][r])+a2[2*j][r]) + bias[2*j]   + ((const float*)&xgv[2*j])[r];
          float v1 = ((a0[2*j+1][r]+a1[2*j+1][r])+a2[2*j+1][r]) + bias[2*j+1] + ((const float*)&xgv[2*j+1])[r];
          float av = (n < 8) ? sigm(v0) : tanha(v0);
          float bv = sigm(v1);
          float pa = __shfl_xor(av, 8);
          float cn = bv*cst[j][r] + av*pa;
          float tc = tanha(cn);
          if (n < 8) cst[j][r] = cn;
          float tcx = __shfl_xor(tc, 8);
          float hv = bv * tcx;                 // valid on n>=8
          float hx = __shfl_xor(hv, 1);
          if (n >= 8 && !(n & 1)){
            _Float16 h0 = (_Float16)hv; _Float16 l0 = (_Float16)(hv - (float)h0);
            _Float16 h1v = (_Float16)hx; _Float16 l1 = (_Float16)(hx - (float)h1v);
            unsigned hw = (unsigned)h16(h0) | ((unsigned)h16(h1v) << 16);
            unsigned lw = (unsigned)h16(l0) | ((unsigned)h16(l1) << 16);
            int m = mout + r;
            awrite((unsigned*)&g_h1hi[t+1][slot*2+j][m][0] + ((n&7)>>1), hw);
            awrite((unsigned*)&g_h1lo[t+1][slot*2+j][m][0] + ((n&7)>>1), lw);
          }
        }
      }
      if (t+1 < TT){
        #pragma unroll
        for (int tl = 0; tl < 4; ++tl) xgv[tl] = xgn[tl];
      }
      asm volatile("s_waitcnt vmcnt(0)" ::: "memory");
      __syncthreads();
      if (tid == 0)
        __hip_atomic_fetch_add(&g_ctr1[t].v, 1u, __ATOMIC_RELAXED, __HIP_MEMORY_SCOPE_AGENT);
    }
    // epilogue: publish final progress so L2's last step can proceed
    if (bid == 0 && tid == 0){
      wait_ge(&g_ctr1[TT-1].v, G1B);
      awrite(&g_prog.v, (unsigned)TT);
    }
  } else {
    // ============ LAYER 2: units [slot*8, slot*8+8), 2 N-tiles ============
    const int b2 = bid - G1B;
    const int ub = b2*8;
    for (int idx = tid; idx < 32*768; idx += 256){
      int r = idx / 768, k = idx - r*768;
      int tile = r >> 4, nn = r & 15;
      int gate = (tile&1) + ((nn>>3)<<1);
      int grow = gate*HH2 + ub + (nn&7);
      float v = (k < HH1) ? Wih2[grow*HH1 + k] : Whh2[grow*HH2 + (k-HH1)];
      _Float16 hi = (_Float16)v;
      sWhi[r*ST2R + k] = hi;
      sWlo[r*ST2R + k] = (_Float16)(v - (float)hi);
    }
    float bias[2];
    #pragma unroll
    for (int tl = 0; tl < 2; ++tl){
      int gate = (tl&1) + ((n>>3)<<1);
      int gi = gate*HH2 + ub + (n&7);
      bias[tl] = bih2[gi] + bhh2[gi];
    }
    asm volatile("s_waitcnt vmcnt(0)" ::: "memory");
    __syncthreads();
    if (tid == 0){
      __hip_atomic_fetch_add(&g_ctr1[TT].v, 1u, __ATOMIC_RELAXED, __HIP_MEMORY_SCOPE_AGENT);
      wait_ge(&g_ctr1[TT].v, NBLK);
    }
    __syncthreads();

    float cst[4] = {0,0,0,0};
    for (int t = 0; t < TT; ++t){
      if (tid == 0){
        wait_ge(&g_prog.v, (unsigned)(t+1));     // h1 slot t+1 published (single-writer line)
        if (t > 0) wait_ge(&g_ctr2[t-1].v, G2B); // h2 slot t published
      }
      __syncthreads();

      f32x4 a0[2], a1[2], a2[2];
      #pragma unroll
      for (int tl = 0; tl < 2; ++tl){ a0[tl]=(f32x4){0,0,0,0}; a1[tl]=a0[tl]; a2[tl]=a0[tl]; }
      const half8* Ah = (const half8*)&g_h1hi[t+1][0][0][0];
      const half8* Al = (const half8*)&g_h1lo[t+1][0][0][0];
      #pragma unroll 4
      for (int ks = 0; ks < 16; ++ks){
        half8 ah = Ah[(ks*4+kq)*BB + mrow];
        half8 al = Al[(ks*4+kq)*BB + mrow];
        int kb = ks*32 + kq*8;
        #pragma unroll
        for (int tl = 0; tl < 2; ++tl){
          half8 bh = *(const half8*)&sWhi[(tl*16+n)*ST2R + kb];
          half8 bl = *(const half8*)&sWlo[(tl*16+n)*ST2R + kb];
          a0[tl] = MFMA16(ah, bh, a0[tl], 0,0,0);
          a1[tl] = MFMA16(ah, bl, a1[tl], 0,0,0);
          a2[tl] = MFMA16(al, bh, a2[tl], 0,0,0);
        }
      }
      const half8* Bh = (const half8*)&g_h2hi[t][0][0][0];
      const half8* Bl = (const half8*)&g_h2lo[t][0][0][0];
      #pragma unroll 4
      for (int ks = 0; ks < 8; ++ks){
        half8 ah = Bh[(ks*4+kq)*BB + mrow];
        half8 al = Bl[(ks*4+kq)*BB + mrow];
        int kb = HH1 + ks*32 + kq*8;
        #pragma unroll
        for (int tl = 0; tl < 2; ++tl){
          half8 bh = *(const half8*)&sWhi[(tl*16+n)*ST2R + kb];
          half8 bl = *(const half8*)&sWlo[(tl*16+n)*ST2R + kb];
          a0[tl] = MFMA16(ah, bh, a0[tl], 0,0,0);
          a1[tl] = MFMA16(ah, bl, a1[tl], 0,0,0);
          a2[tl] = MFMA16(al, bh, a2[tl], 0,0,0);
        }
      }
      #pragma unroll
      for (int r = 0; r < 4; ++r){
        float v0 = ((a0[0][r]+a1[0][r])+a2[0][r]) + bias[0];
        float v1 = ((a0[1][r]+a1[1][r])+a2[1][r]) + bias[1];
        float av = (n < 8) ? sigm(v0) : tanha(v0);
        float bv = sigm(v1);
        float pa = __shfl_xor(av, 8);
        float cn = bv*cst[r] + av*pa;
        float tc = tanha(cn);
        if (n < 8) cst[r] = cn;
        float tcx = __shfl_xor(tc, 8);
        float hv = bv * tcx;
        float hx = __shfl_xor(hv, 1);
        if (n >= 8 && !(n & 1)){
          _Float16 h0 = (_Float16)hv; _Float16 l0 = (_Float16)(hv - (float)h0);
          _Float16 h1v = (_Float16)hx; _Float16 l1 = (_Float16)(hx - (float)h1v);
          unsigned hw = (unsigned)h16(h0) | ((unsigned)h16(h1v) << 16);
          unsigned lw = (unsigned)h16(l0) | ((unsigned)h16(l1) << 16);
          int m = mout + r;
          awrite((unsigned*)&g_h2hi[t+1][b2][m][0] + ((n&7)>>1), hw);
          awrite((unsigned*)&g_h2lo[t+1][b2][m][0] + ((n&7)>>1), lw);
        }
      }
      asm volatile("s_waitcnt vmcnt(0)" ::: "memory");
      __syncthreads();
      if (tid == 0)
        __hip_atomic_fetch_add(&g_ctr2[t].v, 1u, __ATOMIC_RELAXED, __HIP_MEMORY_SCOPE_AGENT);
    }
  }
}

// z = relu(h2_T @ Wfc1^T + bfc1)
__global__ __launch_bounds__(256) void k_fc1(const float* __restrict__ Wfc1, const float* __restrict__ bfc1){
  int b = blockIdx.x;
  for (int task = threadIdx.x; task < 512; task += 256){
    int m = task >> 3, cc = b*8 + (task & 7);
    float acc = bfc1[cc];
    const float* wr = &Wfc1[cc*HH2];
    for (int k = 0; k < HH2; ++k){
      float hvv = (float)g_h2hi[TT][k>>3][m][k&7] + (float)g_h2lo[TT][k>>3][m][k&7];
      acc += hvv * wr[k];
    }
    g_z[m][cc] = fmaxf(acc, 0.f);
  }
}

__global__ __launch_bounds__(256) void k_fc2(const float* __restrict__ Wfc2, const float* __restrict__ bfc2,
                                             float* __restrict__ out){
  for (int task = threadIdx.x; task < BB*7; task += 256){
    int m = task / 7, oc = task % 7;
    float acc = bfc2[oc];
    const float* wr = &Wfc2[oc*FCN];
    const float* zr = &g_z[m][0];
    for (int k = 0; k < FCN; ++k) acc += zr[k]*wr[k];
    out[m*7 + oc] = acc;
  }
  for (int i = threadIdx.x; i < TT+1; i += 256){ g_ctr1[i].v = 0u; g_ctr2[i].v = 0u; }
  if (threadIdx.x == 0) g_prog.v = 0u;
}

extern "C" void kernel_launch(void* const* d_in, const int* in_sizes, int n_in,
                              void* d_out, int out_size, void* d_ws, size_t ws_size,
                              hipStream_t stream){
  (void)in_sizes; (void)n_in; (void)out_size; (void)d_ws; (void)ws_size;
  const float* x    = (const float*)d_in[0];
  const float* Wih1 = (const float*)d_in[1];
  const float* Whh1 = (const float*)d_in[2];
  const float* bih1 = (const float*)d_in[3];
  const float* bhh1 = (const float*)d_in[4];
  const float* Wih2 = (const float*)d_in[5];
  const float* Whh2 = (const float*)d_in[6];
  const float* bih2 = (const float*)d_in[7];
  const float* bhh2 = (const float*)d_in[8];
  const float* Wfc1 = (const float*)d_in[9];
  const float* bfc1 = (const float*)d_in[10];
  const float* Wfc2 = (const float*)d_in[11];
  const float* bfc2 = (const float*)d_in[12];

  hipLaunchKernelGGL(k_split, dim3(TT), dim3(256), 0, stream, x);
  hipLaunchKernelGGL(k_xg,    dim3(G1B*8), dim3(256), 0, stream, Wih1);
  hipLaunchKernelGGL(k_scan,  dim3(NBLK), dim3(256), 0, stream,
                     Whh1, bih1, bhh1, Wih2, Whh2, bih2, bhh2);
  hipLaunchKernelGGL(k_fc1,   dim3(FCN/8), dim3(256), 0, stream, Wfc1, bfc1);
  hipLaunchKernelGGL(k_fc2,   dim3(1), dim3(256), 0, stream, Wfc2, bfc2, (float*)d_out);
}

// Round 5
// 5952.685 us; speedup vs baseline: 1.4305x; 1.2186x over previous
//
#include <hip/hip_runtime.h>

// ---------------- problem constants ----------------
#define TT   512
#define BB   64
#define HH1  512
#define HH2  256
#define DD   204
#define G1B  32          // layer1 blocks (16 units each)
#define NBLK 64          // total scan blocks (32 L1 + 32 L2)
#define ST1R 520         // LDS stride (halfs) for L1 weight stage
#define ST2R 776         // LDS stride for L2 weight stage
#define FCN  512

typedef _Float16 half8 __attribute__((ext_vector_type(8)));
typedef float    f32x4 __attribute__((ext_vector_type(4)));

// xg = x@Wih1^T (permuted cols): [t][blk][col(unit-perm)][batch]
__device__ __align__(16) float g_xg[TT][G1B][64][64];
// h histories in MFMA-A layout: [slot][k-octet][batch][8]
__device__ __align__(16) _Float16 g_h1hi[TT+1][HH1/8][BB][8];
__device__ __align__(16) _Float16 g_h1lo[TT+1][HH1/8][BB][8];
__device__ __align__(16) _Float16 g_h2hi[TT+1][HH2/8][BB][8];
__device__ __align__(16) _Float16 g_h2lo[TT+1][HH2/8][BB][8];
__device__ float g_z[BB][FCN];
// per-block progress flags (no RMW in steady state); one line per flag set
__device__ __align__(128) unsigned g_flag1[32];
__device__ __align__(128) unsigned g_flag2[32];
__device__ unsigned g_ctr0;      // one-time prologue barrier

__device__ __forceinline__ float sigm(float x){ return 1.0f/(1.0f + __expf(-x)); }
__device__ __forceinline__ float tanha(float x){ return 1.0f - 2.0f/(__expf(2.0f*x) + 1.0f); }

__device__ __forceinline__ void awrite(unsigned* p, unsigned v){
  __hip_atomic_store(p, v, __ATOMIC_RELAXED, __HIP_MEMORY_SCOPE_AGENT);
}
__device__ __forceinline__ unsigned aread(unsigned* p){
  return __hip_atomic_load(p, __ATOMIC_RELAXED, __HIP_MEMORY_SCOPE_AGENT);
}
__device__ __forceinline__ void wait_ge(unsigned* c, unsigned target){
  while (aread(c) < target) __builtin_amdgcn_s_sleep(8);
  asm volatile("" ::: "memory");
}
__device__ __forceinline__ unsigned short h16(_Float16 h){
  union { _Float16 f; unsigned short u; } cv; cv.f = h; return cv.u;
}

#define MFMA16 __builtin_amdgcn_mfma_f32_16x16x32_f16

// ---------- xg = x @ Wih1^T : B in registers, A staged per-t in LDS ----------
// grid: 32 blk x 8 t-chunks; 256 thr; wave w = N-tile w (16 permuted cols)
__global__ __launch_bounds__(256) void k_xg(const float* __restrict__ x,
                                            const float* __restrict__ Wih1){
  __shared__ __align__(16) _Float16 sAh[28][64][8];
  __shared__ __align__(16) _Float16 sAl[28][64][8];
  const int tid = threadIdx.x;
  const int blk = blockIdx.x & 31, tc = blockIdx.x >> 5;
  const int l = tid & 63, w = tid >> 6, n = l & 15, kq = l >> 4;

  // B-fragments (hi/lo) into registers
  half8 Bh[7], Bl[7];
  {
    int gate = (w & 1) + ((n >> 3) << 1);
    int unit = ((w >> 1) << 3) + (n & 7);
    int grow = gate*HH1 + blk*16 + unit;
    #pragma unroll
    for (int ks = 0; ks < 7; ++ks){
      int k0 = ks*32 + kq*8;
      half8 hi, lo;
      #pragma unroll
      for (int jj = 0; jj < 8; ++jj){
        float v = (k0 + jj < DD) ? Wih1[grow*DD + k0 + jj] : 0.f;
        _Float16 h = (_Float16)v;
        hi[jj] = h; lo[jj] = (_Float16)(v - (float)h);
      }
      Bh[ks] = hi; Bl[ks] = lo;
    }
  }

  for (int t = tc*64; t < tc*64 + 64; ++t){
    __syncthreads();                 // protect LDS from previous-t readers
    for (int i = tid; i < 64*32; i += 256){
      int ko = i & 31, b = i >> 5;
      if (ko < 28){
        int d0 = ko*8;
        const float* xp = &x[(b*TT + t)*DD];
        float4 va = (d0 + 3 < DD) ? *(const float4*)&xp[d0]     : float4{0,0,0,0};
        float4 vb = (d0 + 7 < DD) ? *(const float4*)&xp[d0 + 4] : float4{0,0,0,0};
        float vv[8] = {va.x,va.y,va.z,va.w, vb.x,vb.y,vb.z,vb.w};
        half8 hi, lo;
        #pragma unroll
        for (int jj = 0; jj < 8; ++jj){
          _Float16 h = (_Float16)vv[jj];
          hi[jj] = h; lo[jj] = (_Float16)(vv[jj] - (float)h);
        }
        *(half8*)&sAh[ko][b][0] = hi;
        *(half8*)&sAl[ko][b][0] = lo;
      }
    }
    __syncthreads();
    #pragma unroll
    for (int mt = 0; mt < 4; ++mt){
      f32x4 a0 = {0,0,0,0}, a1 = a0, a2 = a0;
      #pragma unroll
      for (int ks = 0; ks < 7; ++ks){
        half8 ah = *(const half8*)&sAh[ks*4 + kq][mt*16 + n][0];
        half8 al = *(const half8*)&sAl[ks*4 + kq][mt*16 + n][0];
        a0 = MFMA16(ah, Bh[ks], a0, 0,0,0);
        a1 = MFMA16(ah, Bl[ks], a1, 0,0,0);
        a2 = MFMA16(al, Bh[ks], a2, 0,0,0);
      }
      float4 v4;
      v4.x = (a0[0] + a1[0]) + a2[0];
      v4.y = (a0[1] + a1[1]) + a2[1];
      v4.z = (a0[2] + a1[2]) + a2[2];
      v4.w = (a0[3] + a1[3]) + a2[3];
      *(float4*)&g_xg[t][blk][w*16 + n][mt*16 + kq*4] = v4;
    }
  }
}

// ---------- sequential scan: 64 blocks x 512 thr, weights in REGISTERS ----------
__global__ __launch_bounds__(512) void k_scan(
    const float* __restrict__ Whh1, const float* __restrict__ bih1, const float* __restrict__ bhh1,
    const float* __restrict__ Wih2, const float* __restrict__ Whh2,
    const float* __restrict__ bih2, const float* __restrict__ bhh2)
{
  __shared__ _Float16 sWhi[64*ST1R];   // startup staging only
  __shared__ _Float16 sWlo[64*ST1R];

  const int bid = blockIdx.x;
  const int tid = threadIdx.x;
  const int l  = tid & 63;
  const int w  = tid >> 6;
  const int n  = l & 15;
  const int kq = l >> 4;

  // zero initial states (write-through)
  {
    int eidx = bid*512 + tid;
    unsigned* z1h = (unsigned*)&g_h1hi[0][0][0][0];
    unsigned* z1l = (unsigned*)&g_h1lo[0][0][0][0];
    if (eidx < (HH1*BB)/2){ awrite(z1h + eidx, 0u); awrite(z1l + eidx, 0u); }
    unsigned* z2h = (unsigned*)&g_h2hi[0][0][0][0];
    unsigned* z2l = (unsigned*)&g_h2lo[0][0][0][0];
    if (eidx < (HH2*BB)/2){ awrite(z2h + eidx, 0u); awrite(z2l + eidx, 0u); }
  }

  if (bid < G1B){
    // ===== LAYER 1: units [bid*16, +16); wave (uo = w>>2, mt = w&3) =====
    const int slot = bid, ub = slot*16;
    const int uo = w >> 2, mt = w & 3;
    const int mrow = mt*16 + n, mout = mt*16 + kq*4;

    for (int idx = tid; idx < 64*HH1; idx += 512){
      int r = idx >> 9, k = idx & 511;
      int tile = r >> 4, nn = r & 15;
      int gate = (tile & 1) + ((nn >> 3) << 1);
      int unit = ((tile >> 1) << 3) + (nn & 7);
      int grow = gate*HH1 + ub + unit;
      float v = Whh1[grow*HH1 + k];
      _Float16 hi = (_Float16)v;
      sWhi[r*ST1R + k] = hi;
      sWlo[r*ST1R + k] = (_Float16)(v - (float)hi);
    }
    __syncthreads();
    half8 Bh[2][16], Bl[2][16];
    #pragma unroll
    for (int j = 0; j < 2; ++j){
      int row = (2*uo + j)*16 + n;
      #pragma unroll
      for (int ks = 0; ks < 16; ++ks){
        Bh[j][ks] = *(const half8*)&sWhi[row*ST1R + ks*32 + kq*8];
        Bl[j][ks] = *(const half8*)&sWlo[row*ST1R + ks*32 + kq*8];
      }
    }
    float bias0, bias1;
    {
      int unit = uo*8 + (n & 7);
      int g0 = ((n >> 3) << 1), g1 = g0 + 1;
      bias0 = bih1[g0*HH1 + ub + unit] + bhh1[g0*HH1 + ub + unit];
      bias1 = bih1[g1*HH1 + ub + unit] + bhh1[g1*HH1 + ub + unit];
    }
    asm volatile("s_waitcnt vmcnt(0)" ::: "memory");
    __syncthreads();
    if (tid == 0){
      __hip_atomic_fetch_add(&g_ctr0, 1u, __ATOMIC_RELAXED, __HIP_MEMORY_SCOPE_AGENT);
      wait_ge(&g_ctr0, NBLK);
    }
    __syncthreads();

    float cst[4] = {0,0,0,0};
    for (int t = 0; t < TT; ++t){
      // xg for this step: issue before the poll (independent, precomputed data)
      float4 xg0 = *(const float4*)&g_xg[t][slot][(2*uo)*16 + n][mout];
      float4 xg1 = *(const float4*)&g_xg[t][slot][(2*uo + 1)*16 + n][mout];
      if (w == 0){
        unsigned* f = &g_flag1[l & 31];
        while (true){
          unsigned v = aread(f);
          if (__all(v >= (unsigned)t)) break;
          __builtin_amdgcn_s_sleep(2);
        }
      }
      __syncthreads();

      f32x4 p00 = {0,0,0,0}, p01 = p00, p02 = p00, p10 = p00, p11 = p00, p12 = p00;
      const half8* Ah = (const half8*)&g_h1hi[t][0][0][0];
      const half8* Al = (const half8*)&g_h1lo[t][0][0][0];
      #pragma unroll
      for (int ks = 0; ks < 16; ++ks){
        half8 ah = Ah[(ks*4 + kq)*BB + mrow];
        half8 al = Al[(ks*4 + kq)*BB + mrow];
        p00 = MFMA16(ah, Bh[0][ks], p00, 0,0,0);
        p01 = MFMA16(ah, Bl[0][ks], p01, 0,0,0);
        p02 = MFMA16(al, Bh[0][ks], p02, 0,0,0);
        p10 = MFMA16(ah, Bh[1][ks], p10, 0,0,0);
        p11 = MFMA16(ah, Bl[1][ks], p11, 0,0,0);
        p12 = MFMA16(al, Bh[1][ks], p12, 0,0,0);
      }
      #pragma unroll
      for (int r = 0; r < 4; ++r){
        float v0 = ((p00[r] + p01[r]) + p02[r]) + bias0 + ((const float*)&xg0)[r];
        float v1 = ((p10[r] + p11[r]) + p12[r]) + bias1 + ((const float*)&xg1)[r];
        float av = (n < 8) ? sigm(v0) : tanha(v0);   // i | g
        float bv = sigm(v1);                          // f | o
        float pa = __shfl_xor(av, 8);
        float cn = bv*cst[r] + av*pa;
        float tc = tanha(cn);
        if (n < 8) cst[r] = cn;
        float tcx = __shfl_xor(tc, 8);
        float hv = bv * tcx;                          // valid on n>=8
        float hx = __shfl_xor(hv, 1);
        if (n >= 8 && !(n & 1)){
          _Float16 h0 = (_Float16)hv; _Float16 l0 = (_Float16)(hv - (float)h0);
          _Float16 h1v = (_Float16)hx; _Float16 l1 = (_Float16)(hx - (float)h1v);
          unsigned hw = (unsigned)h16(h0) | ((unsigned)h16(h1v) << 16);
          unsigned lw = (unsigned)h16(l0) | ((unsigned)h16(l1) << 16);
          int m = mout + r;
          awrite((unsigned*)&g_h1hi[t+1][slot*2 + uo][m][0] + ((n & 7) >> 1), hw);
          awrite((unsigned*)&g_h1lo[t+1][slot*2 + uo][m][0] + ((n & 7) >> 1), lw);
        }
      }
      asm volatile("s_waitcnt vmcnt(0)" ::: "memory");
      __syncthreads();
      if (tid == 0) awrite(&g_flag1[slot], (unsigned)(t + 1));
    }
  } else {
    // ===== LAYER 2: units [b2*8, +8); wave (tl = w>>2 in {0,1}, mt = w&3) =====
    // tile row map: row = tl*16 + nn, gate = nn>>2, unit = tl*4 + (nn&3)
    const int b2 = bid - G1B, ub2 = b2*8;
    const int tl = w >> 2, mt = w & 3;
    const int mrow = mt*16 + n, mout = mt*16 + kq*4;

    for (int idx = tid; idx < 32*768; idx += 512){
      int r = idx / 768, k = idx - r*768;
      int tile = r >> 4, nn = r & 15;
      int gate = nn >> 2, unit = tile*4 + (nn & 3);
      int grow = gate*HH2 + ub2 + unit;
      float v = (k < HH1) ? Wih2[grow*HH1 + k] : Whh2[grow*HH2 + (k - HH1)];
      _Float16 hi = (_Float16)v;
      sWhi[r*ST2R + k] = hi;
      sWlo[r*ST2R + k] = (_Float16)(v - (float)hi);
    }
    __syncthreads();
    half8 Bh[24], Bl[24];
    {
      int row = tl*16 + n;
      #pragma unroll
      for (int ks = 0; ks < 24; ++ks){
        Bh[ks] = *(const half8*)&sWhi[row*ST2R + ks*32 + kq*8];
        Bl[ks] = *(const half8*)&sWlo[row*ST2R + ks*32 + kq*8];
      }
    }
    float bias;
    {
      int g = n >> 2, u = n & 3;
      int gi = g*HH2 + ub2 + tl*4 + u;
      bias = bih2[gi] + bhh2[gi];
    }
    asm volatile("s_waitcnt vmcnt(0)" ::: "memory");
    __syncthreads();
    if (tid == 0){
      __hip_atomic_fetch_add(&g_ctr0, 1u, __ATOMIC_RELAXED, __HIP_MEMORY_SCOPE_AGENT);
      wait_ge(&g_ctr0, NBLK);
    }
    __syncthreads();

    float cst[4] = {0,0,0,0};
    for (int t = 0; t < TT; ++t){
      if (w == 0){
        unsigned* f1 = &g_flag1[l & 31];
        unsigned* f2 = &g_flag2[l & 31];
        while (true){
          unsigned a = aread(f1);
          unsigned b = aread(f2);
          if (__all((a >= (unsigned)(t + 1)) && (b >= (unsigned)t))) break;
          __builtin_amdgcn_s_sleep(2);
        }
      }
      __syncthreads();

      f32x4 p0 = {0,0,0,0}, p1 = p0, p2 = p0;
      const half8* Ah = (const half8*)&g_h1hi[t+1][0][0][0];
      const half8* Al = (const half8*)&g_h1lo[t+1][0][0][0];
      #pragma unroll
      for (int ks = 0; ks < 16; ++ks){
        half8 ah = Ah[(ks*4 + kq)*BB + mrow];
        half8 al = Al[(ks*4 + kq)*BB + mrow];
        p0 = MFMA16(ah, Bh[ks], p0, 0,0,0);
        p1 = MFMA16(ah, Bl[ks], p1, 0,0,0);
        p2 = MFMA16(al, Bh[ks], p2, 0,0,0);
      }
      const half8* B2h = (const half8*)&g_h2hi[t][0][0][0];
      const half8* B2l = (const half8*)&g_h2lo[t][0][0][0];
      #pragma unroll
      for (int ks = 0; ks < 8; ++ks){
        half8 ah = B2h[(ks*4 + kq)*BB + mrow];
        half8 al = B2l[(ks*4 + kq)*BB + mrow];
        p0 = MFMA16(ah, Bh[16 + ks], p0, 0,0,0);
        p1 = MFMA16(ah, Bl[16 + ks], p1, 0,0,0);
        p2 = MFMA16(al, Bh[16 + ks], p2, 0,0,0);
      }
      #pragma unroll
      for (int r = 0; r < 4; ++r){
        float v0 = ((p0[r] + p1[r]) + p2[r]) + bias;
        // lane gate: n>>2 = 0:i 1:f 2:g 3:o
        float act = (n >= 8 && n < 12) ? tanha(v0) : sigm(v0);
        float fx = __shfl_xor(act, 4);    // lanes 0..3 receive f
        float gx = __shfl_xor(act, 8);    // lanes 0..3 receive g~
        float cn = fx*cst[r] + act*gx;    // valid on n<4 (act = i)
        float tc = tanha(cn);
        if (n < 4) cst[r] = cn;
        float tcx = __shfl_xor(tc, 12);   // lanes 12..15 receive tanh(c)
        float hv = act * tcx;             // valid on n>=12 (act = o)
        float hx = __shfl_xor(hv, 1);
        if (n >= 12 && !(n & 1)){
          _Float16 h0 = (_Float16)hv; _Float16 l0 = (_Float16)(hv - (float)h0);
          _Float16 h1v = (_Float16)hx; _Float16 l1 = (_Float16)(hx - (float)h1v);
          unsigned hw = (unsigned)h16(h0) | ((unsigned)h16(h1v) << 16);
          unsigned lw = (unsigned)h16(l0) | ((unsigned)h16(l1) << 16);
          int m = mout + r;
          int dw = tl*2 + ((n & 3) >> 1);
          awrite((unsigned*)&g_h2hi[t+1][b2][m][0] + dw, hw);
          awrite((unsigned*)&g_h2lo[t+1][b2][m][0] + dw, lw);
        }
      }
      asm volatile("s_waitcnt vmcnt(0)" ::: "memory");
      __syncthreads();
      if (tid == 0) awrite(&g_flag2[b2], (unsigned)(t + 1));
    }
  }
}

// z = relu(h2_T @ Wfc1^T + bfc1)
__global__ __launch_bounds__(256) void k_fc1(const float* __restrict__ Wfc1, const float* __restrict__ bfc1){
  int b = blockIdx.x;
  for (int task = threadIdx.x; task < 512; task += 256){
    int m = task >> 3, cc = b*8 + (task & 7);
    float acc = bfc1[cc];
    const float* wr = &Wfc1[cc*HH2];
    for (int k = 0; k < HH2; ++k){
      float hvv = (float)g_h2hi[TT][k>>3][m][k&7] + (float)g_h2lo[TT][k>>3][m][k&7];
      acc += hvv * wr[k];
    }
    g_z[m][cc] = fmaxf(acc, 0.f);
  }
}

__global__ __launch_bounds__(256) void k_fc2(const float* __restrict__ Wfc2, const float* __restrict__ bfc2,
                                             float* __restrict__ out){
  for (int task = threadIdx.x; task < BB*7; task += 256){
    int m = task / 7, oc = task % 7;
    float acc = bfc2[oc];
    const float* wr = &Wfc2[oc*FCN];
    const float* zr = &g_z[m][0];
    for (int k = 0; k < FCN; ++k) acc += zr[k]*wr[k];
    out[m*7 + oc] = acc;
  }
  // reset sync state for next (graph-replayed) call
  if (threadIdx.x < 32){ awrite(&g_flag1[threadIdx.x], 0u); awrite(&g_flag2[threadIdx.x], 0u); }
  if (threadIdx.x == 0) awrite(&g_ctr0, 0u);
}

extern "C" void kernel_launch(void* const* d_in, const int* in_sizes, int n_in,
                              void* d_out, int out_size, void* d_ws, size_t ws_size,
                              hipStream_t stream){
  (void)in_sizes; (void)n_in; (void)out_size; (void)d_ws; (void)ws_size;
  const float* x    = (const float*)d_in[0];
  const float* Wih1 = (const float*)d_in[1];
  const float* Whh1 = (const float*)d_in[2];
  const float* bih1 = (const float*)d_in[3];
  const float* bhh1 = (const float*)d_in[4];
  const float* Wih2 = (const float*)d_in[5];
  const float* Whh2 = (const float*)d_in[6];
  const float* bih2 = (const float*)d_in[7];
  const float* bhh2 = (const float*)d_in[8];
  const float* Wfc1 = (const float*)d_in[9];
  const float* bfc1 = (const float*)d_in[10];
  const float* Wfc2 = (const float*)d_in[11];
  const float* bfc2 = (const float*)d_in[12];

  hipLaunchKernelGGL(k_xg,   dim3(G1B*8), dim3(256), 0, stream, x, Wih1);
  hipLaunchKernelGGL(k_scan, dim3(NBLK), dim3(512), 0, stream,
                     Whh1, bih1, bhh1, Wih2, Whh2, bih2, bhh2);
  hipLaunchKernelGGL(k_fc1,  dim3(FCN/8), dim3(256), 0, stream, Wfc1, bfc1);
  hipLaunchKernelGGL(k_fc2,  dim3(1), dim3(256), 0, stream, Wfc2, bfc2, (float*)d_out);
}

// Round 6
// 3919.292 us; speedup vs baseline: 2.1726x; 1.5188x over previous
//
#include <hip/hip_runtime.h>

// ---------------- problem constants ----------------
#define TT   512
#define BB   64
#define HH1  512
#define HH2  256
#define DD   204
#define L1B  64          // layer1 blocks (8 units each)
#define L2B  32          // layer2 blocks (8 units each)
#define NBLK (L1B+L2B)
#define ST1R 520         // LDS row stride (halfs), L1 stage
#define ST2R 776         // LDS row stride (halfs), L2 stage
#define FCN  512

typedef _Float16 half8 __attribute__((ext_vector_type(8)));
typedef float    f32x4 __attribute__((ext_vector_type(4)));

// xg = x@Wih1^T, scan layout: [t][l1-block][col(4gates x 4units x ug)][batch]
__device__ __align__(16) float g_xg[TT][L1B][32][BB];
// h histories, MFMA-A layout: [slot][k-octet][batch][8]
__device__ __align__(16) _Float16 g_h1hi[TT+1][HH1/8][BB][8];
__device__ __align__(16) _Float16 g_h1lo[TT+1][HH1/8][BB][8];
__device__ __align__(16) _Float16 g_h2hi[TT+1][HH2/8][BB][8];
__device__ __align__(16) _Float16 g_h2lo[TT+1][HH2/8][BB][8];
__device__ float g_z[BB][FCN];
// per-block flags, one 128B line each
struct __align__(128) Flag { unsigned v; unsigned pad[31]; };
__device__ Flag g_flag1[L1B];
__device__ Flag g_flag2[L2B];
__device__ unsigned g_ctr0;

__device__ __forceinline__ float sigm(float x){ return 1.0f/(1.0f + __expf(-x)); }
__device__ __forceinline__ float tanha(float x){ return 1.0f - 2.0f/(__expf(2.0f*x) + 1.0f); }

__device__ __forceinline__ void awrite(unsigned* p, unsigned v){
  __hip_atomic_store(p, v, __ATOMIC_RELAXED, __HIP_MEMORY_SCOPE_AGENT);
}
__device__ __forceinline__ unsigned aread(unsigned* p){
  return __hip_atomic_load(p, __ATOMIC_RELAXED, __HIP_MEMORY_SCOPE_AGENT);
}
__device__ __forceinline__ void wait_ge(unsigned* c, unsigned target){
  while (aread(c) < target) __builtin_amdgcn_s_sleep(8);
  asm volatile("" ::: "memory");
}
__device__ __forceinline__ unsigned short h16(_Float16 h){
  union { _Float16 f; unsigned short u; } cv; cv.f = h; return cv.u;
}

#define MFMA16 __builtin_amdgcn_mfma_f32_16x16x32_f16

// ---------- xg = x @ Wih1^T : B in regs, A staged per-t in LDS ----------
// grid: 32 blk x 8 t-chunks; 256 thr; wave w covers cols [w*16, w*16+16)
__global__ __launch_bounds__(256) void k_xg(const float* __restrict__ x,
                                            const float* __restrict__ Wih1){
  __shared__ __align__(16) _Float16 sAh[28][64][8];
  __shared__ __align__(16) _Float16 sAl[28][64][8];
  const int tid = threadIdx.x;
  const int blk = blockIdx.x & 31, tc = blockIdx.x >> 5;
  const int l = tid & 63, w = tid >> 6, n = l & 15, kq = l >> 4;

  // B-fragments (hi/lo) into registers; col c = w*16+n
  // mapping: sb=w>>1 (scan block half), ug=w&1, gate=n>>2, unit=ug*4+(n&3)
  half8 Bh[7], Bl[7];
  {
    int grow = (n>>2)*HH1 + blk*16 + (w>>1)*8 + (w&1)*4 + (n&3);
    #pragma unroll
    for (int ks = 0; ks < 7; ++ks){
      int k0 = ks*32 + kq*8;
      half8 hi, lo;
      #pragma unroll
      for (int jj = 0; jj < 8; ++jj){
        float v = (k0 + jj < DD) ? Wih1[grow*DD + k0 + jj] : 0.f;
        _Float16 h = (_Float16)v;
        hi[jj] = h; lo[jj] = (_Float16)(v - (float)h);
      }
      Bh[ks] = hi; Bl[ks] = lo;
    }
  }

  for (int t = tc*64; t < tc*64 + 64; ++t){
    __syncthreads();
    for (int i = tid; i < 64*32; i += 256){
      int ko = i & 31, b = i >> 5;
      if (ko < 28){
        int d0 = ko*8;
        const float* xp = &x[(b*TT + t)*DD];
        float4 va = (d0 + 3 < DD) ? *(const float4*)&xp[d0]     : float4{0,0,0,0};
        float4 vb = (d0 + 7 < DD) ? *(const float4*)&xp[d0 + 4] : float4{0,0,0,0};
        float vv[8] = {va.x,va.y,va.z,va.w, vb.x,vb.y,vb.z,vb.w};
        half8 hi, lo;
        #pragma unroll
        for (int jj = 0; jj < 8; ++jj){
          _Float16 h = (_Float16)vv[jj];
          hi[jj] = h; lo[jj] = (_Float16)(vv[jj] - (float)h);
        }
        *(half8*)&sAh[ko][b][0] = hi;
        *(half8*)&sAl[ko][b][0] = lo;
      }
    }
    __syncthreads();
    #pragma unroll
    for (int mt = 0; mt < 4; ++mt){
      f32x4 a0 = {0,0,0,0}, a1 = a0, a2 = a0;
      #pragma unroll
      for (int ks = 0; ks < 7; ++ks){
        half8 ah = *(const half8*)&sAh[ks*4 + kq][mt*16 + n][0];
        half8 al = *(const half8*)&sAl[ks*4 + kq][mt*16 + n][0];
        a0 = MFMA16(ah, Bh[ks], a0, 0,0,0);
        a1 = MFMA16(ah, Bl[ks], a1, 0,0,0);
        a2 = MFMA16(al, Bh[ks], a2, 0,0,0);
      }
      float4 v4;
      v4.x = (a0[0] + a1[0]) + a2[0];
      v4.y = (a0[1] + a1[1]) + a2[1];
      v4.z = (a0[2] + a1[2]) + a2[2];
      v4.w = (a0[3] + a1[3]) + a2[3];
      *(float4*)&g_xg[t][blk*2 + (w>>1)][(w&1)*16 + n][mt*16 + kq*4] = v4;
    }
  }
}

// chunked A prefetch/compute macros (static indices only)
#define LOADC(AH, AL, KB, SH, SL) {                         \
  _Pragma("unroll")                                         \
  for (int j = 0; j < 4; ++j){                              \
    AH[j] = SH[(((KB)+j)*4 + kq)*BB + mrow];                \
    AL[j] = SL[(((KB)+j)*4 + kq)*BB + mrow];                \
  } }
#define COMPC_REG(AH, AL, KB) {                             \
  _Pragma("unroll")                                         \
  for (int j = 0; j < 4; ++j){                              \
    p0 = MFMA16(AH[j], Bh[(KB)+j], p0, 0,0,0);              \
    p1 = MFMA16(AH[j], Bl[(KB)+j], p1, 0,0,0);              \
    p2 = MFMA16(AL[j], Bh[(KB)+j], p2, 0,0,0);              \
  } }
#define COMPC_LDS(AH, AL, KB) {                             \
  _Pragma("unroll")                                         \
  for (int j = 0; j < 4; ++j){                              \
    half8 bl = *(const half8*)&sW[1][rowL2*ST2R + ((KB)+j)*32 + kq*8]; \
    p0 = MFMA16(AH[j], Bh[(KB)+j], p0, 0,0,0);              \
    p1 = MFMA16(AH[j], bl, p1, 0,0,0);                      \
    p2 = MFMA16(AL[j], Bh[(KB)+j], p2, 0,0,0);              \
  } }

// ---------- sequential scan: 64 L1 blocks + 32 L2 blocks, 512 thr ----------
__global__ __launch_bounds__(512, 2) void k_scan(
    const float* __restrict__ Whh1, const float* __restrict__ bih1, const float* __restrict__ bhh1,
    const float* __restrict__ Wih2, const float* __restrict__ Whh2,
    const float* __restrict__ bih2, const float* __restrict__ bhh2)
{
  __shared__ _Float16 sW[2][32*ST2R];   // 97 KB: [0]=hi, [1]=lo

  const int bid = blockIdx.x;
  const int tid = threadIdx.x;
  const int l  = tid & 63;
  const int w  = tid >> 6;
  const int n  = l & 15;
  const int kq = l >> 4;
  const int ug = w >> 2;       // unit-group (0/1): units [ug*4, ug*4+4)
  const int mt = w & 3;        // M-tile (batches mt*16..)
  const int mrow = mt*16 + n;
  const int mout = mt*16 + kq*4;

  // zero initial states (write-through)
  {
    int eidx = bid*512 + tid;
    unsigned* z1h = (unsigned*)&g_h1hi[0][0][0][0];
    unsigned* z1l = (unsigned*)&g_h1lo[0][0][0][0];
    if (eidx < (HH1*BB)/2){ awrite(z1h + eidx, 0u); awrite(z1l + eidx, 0u); }
    unsigned* z2h = (unsigned*)&g_h2hi[0][0][0][0];
    unsigned* z2l = (unsigned*)&g_h2lo[0][0][0][0];
    if (eidx < (HH2*BB)/2){ awrite(z2h + eidx, 0u); awrite(z2l + eidx, 0u); }
  }

  if (bid < L1B){
    // ===== LAYER 1: units [b1*8, +8) =====
    const int b1 = bid;
    for (int idx = tid; idx < 32*HH1; idx += 512){
      int r = idx >> 9, k = idx & 511;
      int rug = r >> 4, nn = r & 15;
      int grow = (nn>>2)*HH1 + b1*8 + rug*4 + (nn&3);
      float v = Whh1[grow*HH1 + k];
      _Float16 hi = (_Float16)v;
      sW[0][r*ST1R + k] = hi;
      sW[1][r*ST1R + k] = (_Float16)(v - (float)hi);
    }
    __syncthreads();
    half8 Bh[16], Bl[16];
    {
      int row = ug*16 + n;
      #pragma unroll
      for (int ks = 0; ks < 16; ++ks){
        Bh[ks] = *(const half8*)&sW[0][row*ST1R + ks*32 + kq*8];
        Bl[ks] = *(const half8*)&sW[1][row*ST1R + ks*32 + kq*8];
      }
    }
    float bias;
    {
      int gi = (n>>2)*HH1 + b1*8 + ug*4 + (n&3);
      bias = bih1[gi] + bhh1[gi];
    }
    asm volatile("s_waitcnt vmcnt(0)" ::: "memory");
    __syncthreads();
    if (tid == 0){
      __hip_atomic_fetch_add(&g_ctr0, 1u, __ATOMIC_RELAXED, __HIP_MEMORY_SCOPE_AGENT);
      wait_ge(&g_ctr0, NBLK);
    }
    __syncthreads();

    float cst[4] = {0,0,0,0};
    for (int t = 0; t < TT; ++t){
      float4 xgv = *(const float4*)&g_xg[t][b1][ug*16 + n][mout];
      if (w == 0 && t > 0){
        unsigned* f = &g_flag1[l].v;
        while (!__all(aread(f) >= (unsigned)t)) __builtin_amdgcn_s_sleep(4);
      }
      __syncthreads();

      const half8* Ah = (const half8*)&g_h1hi[t][0][0][0];
      const half8* Al = (const half8*)&g_h1lo[t][0][0][0];
      f32x4 p0 = {0,0,0,0}, p1 = p0, p2 = p0;
      half8 xh[4], xl[4], yh[4], yl[4];
      LOADC(xh, xl, 0, Ah, Al);
      LOADC(yh, yl, 4, Ah, Al);
      COMPC_REG(xh, xl, 0);  LOADC(xh, xl, 8,  Ah, Al);
      COMPC_REG(yh, yl, 4);  LOADC(yh, yl, 12, Ah, Al);
      COMPC_REG(xh, xl, 8);
      COMPC_REG(yh, yl, 12);

      #pragma unroll
      for (int r = 0; r < 4; ++r){
        float v = ((p0[r] + p1[r]) + p2[r]) + bias + ((const float*)&xgv)[r];
        // lane gate: n>>2 = 0:i 1:f 2:g 3:o  (units ug*4 + (n&3))
        float act = (n >= 8 && n < 12) ? tanha(v) : sigm(v);
        float fx = __shfl_xor(act, 4);
        float gx = __shfl_xor(act, 8);
        float cn = fx*cst[r] + act*gx;       // valid on n<4 (act = i)
        float tc = tanha(cn);
        if (n < 4) cst[r] = cn;
        float tcx = __shfl_xor(tc, 12);
        float hv = act * tcx;                // valid on n>=12 (act = o)
        float hx = __shfl_xor(hv, 1);
        if (n >= 12 && !(n & 1)){
          _Float16 h0 = (_Float16)hv; _Float16 l0 = (_Float16)(hv - (float)h0);
          _Float16 h1v = (_Float16)hx; _Float16 l1 = (_Float16)(hx - (float)h1v);
          unsigned hw = (unsigned)h16(h0) | ((unsigned)h16(h1v) << 16);
          unsigned lw = (unsigned)h16(l0) | ((unsigned)h16(l1) << 16);
          int m = mout + r;
          int dw = ug*2 + ((n & 3) >> 1);
          awrite((unsigned*)&g_h1hi[t+1][b1][m][0] + dw, hw);
          awrite((unsigned*)&g_h1lo[t+1][b1][m][0] + dw, lw);
        }
      }
      asm volatile("s_waitcnt vmcnt(0)" ::: "memory");
      __syncthreads();
      if (tid == 0) awrite(&g_flag1[b1].v, (unsigned)(t + 1));
    }
  } else {
    // ===== LAYER 2: units [b2*8, +8); K = 768 (h1 | h2) =====
    const int b2 = bid - L1B;
    const int rowL2 = ug*16 + n;
    for (int idx = tid; idx < 32*768; idx += 512){
      int r = idx / 768, k = idx - r*768;
      int rug = r >> 4, nn = r & 15;
      int grow = (nn>>2)*HH2 + b2*8 + rug*4 + (nn&3);
      float v = (k < HH1) ? Wih2[grow*HH1 + k] : Whh2[grow*HH2 + (k - HH1)];
      _Float16 hi = (_Float16)v;
      sW[0][r*ST2R + k] = hi;
      sW[1][r*ST2R + k] = (_Float16)(v - (float)hi);
    }
    __syncthreads();
    half8 Bh[24];
    #pragma unroll
    for (int ks = 0; ks < 24; ++ks)
      Bh[ks] = *(const half8*)&sW[0][rowL2*ST2R + ks*32 + kq*8];
    float bias;
    {
      int gi = (n>>2)*HH2 + b2*8 + ug*4 + (n&3);
      bias = bih2[gi] + bhh2[gi];
    }
    asm volatile("s_waitcnt vmcnt(0)" ::: "memory");
    __syncthreads();
    if (tid == 0){
      __hip_atomic_fetch_add(&g_ctr0, 1u, __ATOMIC_RELAXED, __HIP_MEMORY_SCOPE_AGENT);
      wait_ge(&g_ctr0, NBLK);
    }
    __syncthreads();

    float cst[4] = {0,0,0,0};
    for (int t = 0; t < TT; ++t){
      if (w == 0){
        unsigned* f1 = &g_flag1[l].v;
        unsigned* f2 = &g_flag2[l & 31].v;
        while (true){
          unsigned a = aread(f1);
          unsigned b = aread(f2);
          if (__all(a >= (unsigned)(t + 1) && b >= (unsigned)t)) break;
          __builtin_amdgcn_s_sleep(4);
        }
      }
      __syncthreads();

      const half8* Ah = (const half8*)&g_h1hi[t+1][0][0][0];
      const half8* Al = (const half8*)&g_h1lo[t+1][0][0][0];
      const half8* Ch = (const half8*)&g_h2hi[t][0][0][0];
      const half8* Cl = (const half8*)&g_h2lo[t][0][0][0];
      f32x4 p0 = {0,0,0,0}, p1 = p0, p2 = p0;
      half8 xh[4], xl[4], yh[4], yl[4];
      LOADC(xh, xl, 0, Ah, Al);
      LOADC(yh, yl, 4, Ah, Al);
      COMPC_LDS(xh, xl, 0);   LOADC(xh, xl, 8,  Ah, Al);
      COMPC_LDS(yh, yl, 4);   LOADC(yh, yl, 12, Ah, Al);
      COMPC_LDS(xh, xl, 8);   LOADC(xh, xl, 0,  Ch, Cl);
      COMPC_LDS(yh, yl, 12);  LOADC(yh, yl, 4,  Ch, Cl);
      COMPC_LDS(xh, xl, 16);
      COMPC_LDS(yh, yl, 20);

      #pragma unroll
      for (int r = 0; r < 4; ++r){
        float v = ((p0[r] + p1[r]) + p2[r]) + bias;
        float act = (n >= 8 && n < 12) ? tanha(v) : sigm(v);
        float fx = __shfl_xor(act, 4);
        float gx = __shfl_xor(act, 8);
        float cn = fx*cst[r] + act*gx;
        float tc = tanha(cn);
        if (n < 4) cst[r] = cn;
        float tcx = __shfl_xor(tc, 12);
        float hv = act * tcx;
        float hx = __shfl_xor(hv, 1);
        if (n >= 12 && !(n & 1)){
          _Float16 h0 = (_Float16)hv; _Float16 l0 = (_Float16)(hv - (float)h0);
          _Float16 h1v = (_Float16)hx; _Float16 l1 = (_Float16)(hx - (float)h1v);
          unsigned hw = (unsigned)h16(h0) | ((unsigned)h16(h1v) << 16);
          unsigned lw = (unsigned)h16(l0) | ((unsigned)h16(l1) << 16);
          int m = mout + r;
          int dw = ug*2 + ((n & 3) >> 1);
          awrite((unsigned*)&g_h2hi[t+1][b2][m][0] + dw, hw);
          awrite((unsigned*)&g_h2lo[t+1][b2][m][0] + dw, lw);
        }
      }
      asm volatile("s_waitcnt vmcnt(0)" ::: "memory");
      __syncthreads();
      if (tid == 0) awrite(&g_flag2[b2].v, (unsigned)(t + 1));
    }
  }
}

// z = relu(h2_T @ Wfc1^T + bfc1)
__global__ __launch_bounds__(256) void k_fc1(const float* __restrict__ Wfc1, const float* __restrict__ bfc1){
  int b = blockIdx.x;
  for (int task = threadIdx.x; task < 512; task += 256){
    int m = task >> 3, cc = b*8 + (task & 7);
    float acc = bfc1[cc];
    const float* wr = &Wfc1[cc*HH2];
    for (int k = 0; k < HH2; ++k){
      float hvv = (float)g_h2hi[TT][k>>3][m][k&7] + (float)g_h2lo[TT][k>>3][m][k&7];
      acc += hvv * wr[k];
    }
    g_z[m][cc] = fmaxf(acc, 0.f);
  }
}

__global__ __launch_bounds__(256) void k_fc2(const float* __restrict__ Wfc2, const float* __restrict__ bfc2,
                                             float* __restrict__ out){
  for (int task = threadIdx.x; task < BB*7; task += 256){
    int m = task / 7, oc = task % 7;
    float acc = bfc2[oc];
    const float* wr = &Wfc2[oc*FCN];
    const float* zr = &g_z[m][0];
    for (int k = 0; k < FCN; ++k) acc += zr[k]*wr[k];
    out[m*7 + oc] = acc;
  }
  if (threadIdx.x < L1B) awrite(&g_flag1[threadIdx.x].v, 0u);
  if (threadIdx.x < L2B) awrite(&g_flag2[threadIdx.x].v, 0u);
  if (threadIdx.x == 0)  awrite(&g_ctr0, 0u);
}

extern "C" void kernel_launch(void* const* d_in, const int* in_sizes, int n_in,
                              void* d_out, int out_size, void* d_ws, size_t ws_size,
                              hipStream_t stream){
  (void)in_sizes; (void)n_in; (void)out_size; (void)d_ws; (void)ws_size;
  const float* x    = (const float*)d_in[0];
  const float* Wih1 = (const float*)d_in[1];
  const float* Whh1 = (const float*)d_in[2];
  const float* bih1 = (const float*)d_in[3];
  const float* bhh1 = (const float*)d_in[4];
  const float* Wih2 = (const float*)d_in[5];
  const float* Whh2 = (const float*)d_in[6];
  const float* bih2 = (const float*)d_in[7];
  const float* bhh2 = (const float*)d_in[8];
  const float* Wfc1 = (const float*)d_in[9];
  const float* bfc1 = (const float*)d_in[10];
  const float* Wfc2 = (const float*)d_in[11];
  const float* bfc2 = (const float*)d_in[12];

  hipLaunchKernelGGL(k_xg,   dim3(256), dim3(256), 0, stream, x, Wih1);
  hipLaunchKernelGGL(k_scan, dim3(NBLK), dim3(512), 0, stream,
                     Whh1, bih1, bhh1, Wih2, Whh2, bih2, bhh2);
  hipLaunchKernelGGL(k_fc1,  dim3(FCN/8), dim3(256), 0, stream, Wfc1, bfc1);
  hipLaunchKernelGGL(k_fc2,  dim3(1), dim3(256), 0, stream, Wfc2, bfc2, (float*)d_out);
}